// Round 2
// baseline (977.907 us; speedup 1.0000x reference)
//
#include <hip/hip_runtime.h>

#define BATCH 8
#define N 2048
#define NITERS 20

// ---------------------------------------------------------------------------
// Linear-domain Sinkhorn (matrix scaling). K = exp(Z0) is iteration-invariant:
//   F_i = sum_j K_ij * R_j          (row pass; R = exp(-g))
//   S_j = sum_i K_ij / F_i          (per-wave partials + combine)
//   R_j = 1 / S_j
// Output: P_ij = K_ij * (1/F_i) * R_j  == exp(Z0 - f - g)
// z in ~[-6,6] so K in [2e-3, 4e2]; all sums ~3e3 -> fp32 safe, err ~1e-6 rel.
// ---------------------------------------------------------------------------

static __device__ __forceinline__ float wave_sum(float v) {
#pragma unroll
  for (int o = 32; o > 0; o >>= 1) v += __shfl_xor(v, o, 64);
  return v;
}

// K = exp(z0); also init R = 1.
__global__ __launch_bounds__(256) void precompute_kernel(
    const float* __restrict__ z0, float* __restrict__ K,
    float* __restrict__ R) {
  const size_t total4 = (size_t)BATCH * N * N / 4;
  const size_t gid = (size_t)blockIdx.x * 256 + threadIdx.x;
  const float4* z4 = reinterpret_cast<const float4*>(z0);
  float4* k4 = reinterpret_cast<float4*>(K);
  for (size_t i = gid; i < total4; i += (size_t)gridDim.x * 256) {
    const float4 z = z4[i];
    float4 e;
    e.x = __expf(z.x);
    e.y = __expf(z.y);
    e.z = __expf(z.z);
    e.w = __expf(z.w);
    k4[i] = e;
  }
  if (gid < (BATCH * N) / 4) {
    reinterpret_cast<float4*>(R)[gid] = make_float4(1.f, 1.f, 1.f, 1.f);
  }
}

__global__ void init_R_kernel(float* __restrict__ R) {
  const int i = blockIdx.x * blockDim.x + threadIdx.x;
  if (i < (BATCH * N) / 4)
    reinterpret_cast<float4*>(R)[i] = make_float4(1.f, 1.f, 1.f, 1.f);
}

// One wave handles RPW consecutive rows of one batch; lane owns 32 fixed
// columns (8 x float4). R kept in registers across the wave's rows.
// PRE: src is K = exp(z0). !PRE: src is z0, exp applied on the fly.
template <bool PRE, int RPW>
__global__ __launch_bounds__(256) void row_kernel(
    const float* __restrict__ src, const float* __restrict__ R,
    float* __restrict__ invF, float* __restrict__ part) {
  constexpr int CH = N / RPW;
  const int lane = threadIdx.x & 63;
  const int w = threadIdx.x >> 6;
  const int b = blockIdx.y;
  const int chunk = blockIdx.x * 4 + w;
  const int row0 = chunk * RPW;

  const float4* r4 = reinterpret_cast<const float4*>(R + (size_t)b * N);
  float4 rv[8], acc[8];
#pragma unroll
  for (int k = 0; k < 8; ++k) {
    rv[k] = r4[lane + 64 * k];
    acc[k] = make_float4(0.f, 0.f, 0.f, 0.f);
  }

  for (int r = 0; r < RPW; ++r) {
    const int row = row0 + r;
    const float4* z4 =
        reinterpret_cast<const float4*>(src + ((size_t)b * N + row) * N);
    float4 zv[8];
#pragma unroll
    for (int k = 0; k < 8; ++k) zv[k] = z4[lane + 64 * k];
    if (!PRE) {
#pragma unroll
      for (int k = 0; k < 8; ++k) {
        zv[k].x = __expf(zv[k].x);
        zv[k].y = __expf(zv[k].y);
        zv[k].z = __expf(zv[k].z);
        zv[k].w = __expf(zv[k].w);
      }
    }

    float s0 = 0.f, s1 = 0.f;
#pragma unroll
    for (int k = 0; k < 8; ++k) {
      s0 += zv[k].x * rv[k].x;
      s1 += zv[k].y * rv[k].y;
      s0 += zv[k].z * rv[k].z;
      s1 += zv[k].w * rv[k].w;
    }
    float s = wave_sum(s0 + s1);
    const float inv = 1.0f / s;
    if (lane == 0) invF[(size_t)b * N + row] = inv;

#pragma unroll
    for (int k = 0; k < 8; ++k) {
      acc[k].x += zv[k].x * inv;
      acc[k].y += zv[k].y * inv;
      acc[k].z += zv[k].z * inv;
      acc[k].w += zv[k].w * inv;
    }
  }

  float4* p4 =
      reinterpret_cast<float4*>(part + ((size_t)b * CH + chunk) * N);
#pragma unroll
  for (int k = 0; k < 8; ++k) p4[lane + 64 * k] = acc[k];
}

// R_j = 1 / (sum over CH chunk-partials). 4 threads per (batch, column).
template <int CH>
__global__ __launch_bounds__(256) void combine_kernel(
    const float* __restrict__ part, float* __restrict__ R) {
  const int gid = blockIdx.x * 256 + threadIdx.x;
  const int col_id = gid >> 2;  // b*N + j
  const int sub = gid & 3;
  const int b = col_id >> 11;
  const int j = col_id & (N - 1);
  const float* p = part + (size_t)b * CH * N + j + (size_t)sub * N;
  float s = 0.f;
#pragma unroll
  for (int c = 0; c < CH / 4; ++c) s += p[(size_t)c * 4 * N];
  s += __shfl_xor(s, 1, 64);
  s += __shfl_xor(s, 2, 64);
  if (sub == 0) R[col_id] = 1.0f / s;
}

template <bool PRE>
__global__ __launch_bounds__(256) void final_kernel(
    const float* __restrict__ src, const float* __restrict__ invF,
    const float* __restrict__ R, float* __restrict__ out) {
  const int b = blockIdx.y;
  const int row = blockIdx.x;
  const float fi = invF[(size_t)b * N + row];
  const float4* z4 =
      reinterpret_cast<const float4*>(src + ((size_t)b * N + row) * N);
  const float4* r4 = reinterpret_cast<const float4*>(R + (size_t)b * N);
  float4* o4 = reinterpret_cast<float4*>(out + ((size_t)b * N + row) * N);
#pragma unroll
  for (int k = 0; k < 2; ++k) {
    const int i = threadIdx.x + 256 * k;
    float4 z = z4[i];
    const float4 r = r4[i];
    if (!PRE) {
      z.x = __expf(z.x);
      z.y = __expf(z.y);
      z.z = __expf(z.z);
      z.w = __expf(z.w);
    }
    float4 o;
    o.x = z.x * fi * r.x;
    o.y = z.y * fi * r.y;
    o.z = z.z * fi * r.z;
    o.w = z.w * fi * r.w;
    o4[i] = o;
  }
}

extern "C" void kernel_launch(void* const* d_in, const int* in_sizes, int n_in,
                              void* d_out, int out_size, void* d_ws,
                              size_t ws_size, hipStream_t stream) {
  const float* z0 = (const float*)d_in[0];
  float* out = (float*)d_out;

  float* invF = (float*)d_ws;              // BATCH*N
  float* R = invF + (size_t)BATCH * N;     // BATCH*N
  float* part = R + (size_t)BATCH * N;     // BATCH*CH*N

  const size_t small_b = 2ull * BATCH * N * sizeof(float);
  const size_t part8_b = (size_t)BATCH * (N / 8) * N * sizeof(float);
  const size_t part32_b = (size_t)BATCH * (N / 32) * N * sizeof(float);
  const size_t K_b = (size_t)BATCH * N * N * sizeof(float);

  if (ws_size >= small_b + part8_b + K_b) {
    // Fast path: precomputed K = exp(z0) in workspace.
    constexpr int RPW = 8;
    constexpr int CH = N / RPW;
    float* K = part + (size_t)BATCH * CH * N;
    precompute_kernel<<<dim3(2048), dim3(256), 0, stream>>>(z0, K, R);
    for (int it = 0; it < NITERS; ++it) {
      row_kernel<true, RPW>
          <<<dim3(N / (4 * RPW), BATCH), dim3(256), 0, stream>>>(K, R, invF,
                                                                 part);
      combine_kernel<CH>
          <<<dim3((BATCH * N * 4) / 256), dim3(256), 0, stream>>>(part, R);
    }
    final_kernel<true>
        <<<dim3(N, BATCH), dim3(256), 0, stream>>>(K, invF, R, out);
  } else if (ws_size >= small_b + part8_b) {
    constexpr int RPW = 8;
    constexpr int CH = N / RPW;
    init_R_kernel<<<dim3(16), dim3(128), 0, stream>>>(R);
    for (int it = 0; it < NITERS; ++it) {
      row_kernel<false, RPW>
          <<<dim3(N / (4 * RPW), BATCH), dim3(256), 0, stream>>>(z0, R, invF,
                                                                 part);
      combine_kernel<CH>
          <<<dim3((BATCH * N * 4) / 256), dim3(256), 0, stream>>>(part, R);
    }
    final_kernel<false>
        <<<dim3(N, BATCH), dim3(256), 0, stream>>>(z0, invF, R, out);
  } else {
    constexpr int RPW = 32;
    constexpr int CH = N / RPW;
    init_R_kernel<<<dim3(16), dim3(128), 0, stream>>>(R);
    for (int it = 0; it < NITERS; ++it) {
      row_kernel<false, RPW>
          <<<dim3(N / (4 * RPW), BATCH), dim3(256), 0, stream>>>(z0, R, invF,
                                                                 part);
      combine_kernel<CH>
          <<<dim3((BATCH * N * 4) / 256), dim3(256), 0, stream>>>(part, R);
    }
    final_kernel<false>
        <<<dim3(N, BATCH), dim3(256), 0, stream>>>(z0, invF, R, out);
  }
}

// Round 3
// 542.772 us; speedup vs baseline: 1.8017x; 1.8017x over previous
//
#include <hip/hip_runtime.h>
#include <hip/hip_fp16.h>

#define BATCH 8
#define N 2048
#define NITERS 20

// ---------------------------------------------------------------------------
// Linear-domain Sinkhorn (matrix scaling), fp16 kernel matrix:
//   K = exp(z0) (fp16), KT = K^T (fp16)   [one-time precompute, LDS transpose]
//   repeat 20x:  invF_i = 1 / sum_j K_ij  * R_j      (row GEMV)
//                R_j    = 1 / sum_i KT_ji * invF_i   (col GEMV, row-major KT)
//   out_ij = K_ij * invF_i * R_j
// K in [4e-3, 3e2] -> fp16-safe. Sinkhorn is contractive, so the fp16
// perturbation gives ~1e-3 RELATIVE error; P_max ~ 0.1 -> abs err ~1e-4.
// K + KT = 134 MB -> fully Infinity-Cache resident across all 40 phases.
// ---------------------------------------------------------------------------

struct alignas(8) Half4 { __half x, y, z, w; };

static __device__ __forceinline__ float wave_sum(float v) {
#pragma unroll
  for (int o = 32; o > 0; o >>= 1) v += __shfl_xor(v, o, 64);
  return v;
}

__global__ __launch_bounds__(256) void init_R_kernel(float* __restrict__ R) {
  const int i = blockIdx.x * 256 + threadIdx.x;
  if (i < (BATCH * N) / 4)
    reinterpret_cast<float4*>(R)[i] = make_float4(1.f, 1.f, 1.f, 1.f);
}

// K = exp(z0) as fp16, and KT = K^T as fp16, via a 64x64 LDS float tile.
// Tile stride 65 floats -> worst LDS aliasing is 2-way (free).
__global__ __launch_bounds__(256) void exp_transpose_kernel(
    const float* __restrict__ z0, __half* __restrict__ K,
    __half* __restrict__ KT) {
  __shared__ float t[64][65];
  const int b = blockIdx.z;
  const int R0 = blockIdx.y * 64, C0 = blockIdx.x * 64;
  const int q = threadIdx.x & 15, r16 = threadIdx.x >> 4;
#pragma unroll
  for (int p = 0; p < 4; ++p) {
    const int row = p * 16 + r16;
    const float4 z = *reinterpret_cast<const float4*>(
        z0 + ((size_t)b * N + R0 + row) * N + C0 + q * 4);
    const float e0 = __expf(z.x), e1 = __expf(z.y), e2 = __expf(z.z),
                e3 = __expf(z.w);
    const Half4 h = {__float2half_rn(e0), __float2half_rn(e1),
                     __float2half_rn(e2), __float2half_rn(e3)};
    *reinterpret_cast<Half4*>(K + ((size_t)b * N + R0 + row) * N + C0 +
                              q * 4) = h;
    t[row][q * 4 + 0] = e0;
    t[row][q * 4 + 1] = e1;
    t[row][q * 4 + 2] = e2;
    t[row][q * 4 + 3] = e3;
  }
  __syncthreads();
#pragma unroll
  for (int p = 0; p < 4; ++p) {
    const int jr = p * 16 + r16;  // KT row within tile == original column
    const Half4 h = {
        __float2half_rn(t[q * 4 + 0][jr]), __float2half_rn(t[q * 4 + 1][jr]),
        __float2half_rn(t[q * 4 + 2][jr]), __float2half_rn(t[q * 4 + 3][jr])};
    *reinterpret_cast<Half4*>(KT + ((size_t)b * N + C0 + jr) * N + R0 +
                              q * 4) = h;
  }
}

// o[b][row] = 1 / sum_j M[b][row][j] * v[b][j].  One wave per row; the 8 KB
// vector v is staged in LDS per block (4 rows share it).
__global__ __launch_bounds__(256) void gemv_recip_kernel(
    const __half* __restrict__ M, const float* __restrict__ v,
    float* __restrict__ o) {
  __shared__ float vs[N];
  const int b = blockIdx.y;
  {
    const float4* v4 = reinterpret_cast<const float4*>(v + (size_t)b * N);
    float4* s4 = reinterpret_cast<float4*>(vs);
#pragma unroll
    for (int k = 0; k < 2; ++k)
      s4[threadIdx.x + 256 * k] = v4[threadIdx.x + 256 * k];
  }
  __syncthreads();
  const int lane = threadIdx.x & 63;
  const int w = threadIdx.x >> 6;
  const int row = blockIdx.x * 4 + w;
  const float4* m4 =
      reinterpret_cast<const float4*>(M + ((size_t)b * N + row) * N);
  float4 raw[4];
#pragma unroll
  for (int c = 0; c < 4; ++c) raw[c] = m4[c * 64 + lane];  // 8 halfs each
  float s0 = 0.f, s1 = 0.f;
#pragma unroll
  for (int c = 0; c < 4; ++c) {
    const __half2* h = reinterpret_cast<const __half2*>(&raw[c]);
    const float4* vp =
        reinterpret_cast<const float4*>(&vs[c * 512 + lane * 8]);
    const float4 va = vp[0], vb = vp[1];
    float2 f;
    f = __half22float2(h[0]); s0 += f.x * va.x; s1 += f.y * va.y;
    f = __half22float2(h[1]); s0 += f.x * va.z; s1 += f.y * va.w;
    f = __half22float2(h[2]); s0 += f.x * vb.x; s1 += f.y * vb.y;
    f = __half22float2(h[3]); s0 += f.x * vb.z; s1 += f.y * vb.w;
  }
  const float s = wave_sum(s0 + s1);
  if (lane == 0) o[(size_t)b * N + row] = 1.0f / s;
}

// out[b][i][j] = K[b][i][j] * invF[b][i] * R[b][j]
__global__ __launch_bounds__(256) void final_fp16_kernel(
    const __half* __restrict__ K, const float* __restrict__ invF,
    const float* __restrict__ R, float* __restrict__ out) {
  __shared__ float vs[N];
  const int b = blockIdx.y;
  {
    const float4* v4 = reinterpret_cast<const float4*>(R + (size_t)b * N);
    float4* s4 = reinterpret_cast<float4*>(vs);
#pragma unroll
    for (int k = 0; k < 2; ++k)
      s4[threadIdx.x + 256 * k] = v4[threadIdx.x + 256 * k];
  }
  __syncthreads();
  const int lane = threadIdx.x & 63;
  const int w = threadIdx.x >> 6;
  const int row = blockIdx.x * 4 + w;
  const float fi = invF[(size_t)b * N + row];
  const float4* m4 =
      reinterpret_cast<const float4*>(K + ((size_t)b * N + row) * N);
  float4* o4 = reinterpret_cast<float4*>(out + ((size_t)b * N + row) * N);
#pragma unroll
  for (int c = 0; c < 4; ++c) {
    const float4 raw = m4[c * 64 + lane];
    const __half2* h = reinterpret_cast<const __half2*>(&raw);
    const float4* vp =
        reinterpret_cast<const float4*>(&vs[c * 512 + lane * 8]);
    const float4 va = vp[0], vb = vp[1];
    float4 oa, ob;
    float2 f;
    f = __half22float2(h[0]); oa.x = f.x * fi * va.x; oa.y = f.y * fi * va.y;
    f = __half22float2(h[1]); oa.z = f.x * fi * va.z; oa.w = f.y * fi * va.w;
    f = __half22float2(h[2]); ob.x = f.x * fi * vb.x; ob.y = f.y * fi * vb.y;
    f = __half22float2(h[3]); ob.z = f.x * fi * vb.z; ob.w = f.y * fi * vb.w;
    o4[(c * 64 + lane) * 2 + 0] = oa;
    o4[(c * 64 + lane) * 2 + 1] = ob;
  }
}

// ------------------------- fallback (small ws) ------------------------------
// Round-1/2 style: on-the-fly exp row pass + partial combine. Only used if
// ws_size can't hold K+KT (observed ws is 512 MiB, so normally unused).
template <int RPW>
__global__ __launch_bounds__(256) void row_fb_kernel(
    const float* __restrict__ z0, const float* __restrict__ R,
    float* __restrict__ invF, float* __restrict__ part) {
  constexpr int CH = N / RPW;
  const int lane = threadIdx.x & 63;
  const int w = threadIdx.x >> 6;
  const int b = blockIdx.y;
  const int chunk = blockIdx.x * 4 + w;
  const int row0 = chunk * RPW;
  const float4* r4 = reinterpret_cast<const float4*>(R + (size_t)b * N);
  float4 rv[8], acc[8];
#pragma unroll
  for (int k = 0; k < 8; ++k) {
    rv[k] = r4[lane + 64 * k];
    acc[k] = make_float4(0.f, 0.f, 0.f, 0.f);
  }
  for (int r = 0; r < RPW; ++r) {
    const int row = row0 + r;
    const float4* z4 =
        reinterpret_cast<const float4*>(z0 + ((size_t)b * N + row) * N);
    float4 zv[8];
#pragma unroll
    for (int k = 0; k < 8; ++k) {
      zv[k] = z4[lane + 64 * k];
      zv[k].x = __expf(zv[k].x); zv[k].y = __expf(zv[k].y);
      zv[k].z = __expf(zv[k].z); zv[k].w = __expf(zv[k].w);
    }
    float s0 = 0.f, s1 = 0.f;
#pragma unroll
    for (int k = 0; k < 8; ++k) {
      s0 += zv[k].x * rv[k].x; s1 += zv[k].y * rv[k].y;
      s0 += zv[k].z * rv[k].z; s1 += zv[k].w * rv[k].w;
    }
    const float inv = 1.0f / wave_sum(s0 + s1);
    if (lane == 0) invF[(size_t)b * N + row] = inv;
#pragma unroll
    for (int k = 0; k < 8; ++k) {
      acc[k].x += zv[k].x * inv; acc[k].y += zv[k].y * inv;
      acc[k].z += zv[k].z * inv; acc[k].w += zv[k].w * inv;
    }
  }
  float4* p4 = reinterpret_cast<float4*>(part + ((size_t)b * CH + chunk) * N);
#pragma unroll
  for (int k = 0; k < 8; ++k) p4[lane + 64 * k] = acc[k];
}

template <int CH>
__global__ __launch_bounds__(256) void combine_fb_kernel(
    const float* __restrict__ part, float* __restrict__ R) {
  const int gid = blockIdx.x * 256 + threadIdx.x;
  const int col_id = gid >> 2;
  const int sub = gid & 3;
  const int b = col_id >> 11;
  const int j = col_id & (N - 1);
  const float* p = part + (size_t)b * CH * N + j + (size_t)sub * N;
  float s = 0.f;
#pragma unroll
  for (int c = 0; c < CH / 4; ++c) s += p[(size_t)c * 4 * N];
  s += __shfl_xor(s, 1, 64);
  s += __shfl_xor(s, 2, 64);
  if (sub == 0) R[col_id] = 1.0f / s;
}

__global__ __launch_bounds__(256) void final_fb_kernel(
    const float* __restrict__ z0, const float* __restrict__ invF,
    const float* __restrict__ R, float* __restrict__ out) {
  const int b = blockIdx.y;
  const int row = blockIdx.x;
  const float fi = invF[(size_t)b * N + row];
  const float4* z4 =
      reinterpret_cast<const float4*>(z0 + ((size_t)b * N + row) * N);
  const float4* r4 = reinterpret_cast<const float4*>(R + (size_t)b * N);
  float4* o4 = reinterpret_cast<float4*>(out + ((size_t)b * N + row) * N);
#pragma unroll
  for (int k = 0; k < 2; ++k) {
    const int i = threadIdx.x + 256 * k;
    const float4 z = z4[i];
    const float4 r = r4[i];
    float4 o;
    o.x = __expf(z.x) * fi * r.x; o.y = __expf(z.y) * fi * r.y;
    o.z = __expf(z.z) * fi * r.z; o.w = __expf(z.w) * fi * r.w;
    o4[i] = o;
  }
}

extern "C" void kernel_launch(void* const* d_in, const int* in_sizes, int n_in,
                              void* d_out, int out_size, void* d_ws,
                              size_t ws_size, hipStream_t stream) {
  const float* z0 = (const float*)d_in[0];
  float* out = (float*)d_out;

  const size_t KE = (size_t)BATCH * N * N;  // elements per matrix
  const size_t need =
      2 * KE * sizeof(__half) + 2 * (size_t)BATCH * N * sizeof(float);

  if (ws_size >= need) {
    __half* K = (__half*)d_ws;
    __half* KT = K + KE;
    float* invF = (float*)(KT + KE);
    float* R = invF + (size_t)BATCH * N;

    exp_transpose_kernel<<<dim3(32, 32, 8), dim3(256), 0, stream>>>(z0, K, KT);
    init_R_kernel<<<dim3(16), dim3(256), 0, stream>>>(R);
    for (int it = 0; it < NITERS; ++it) {
      gemv_recip_kernel<<<dim3(N / 4, BATCH), dim3(256), 0, stream>>>(K, R,
                                                                      invF);
      gemv_recip_kernel<<<dim3(N / 4, BATCH), dim3(256), 0, stream>>>(KT, invF,
                                                                      R);
    }
    final_fp16_kernel<<<dim3(N / 4, BATCH), dim3(256), 0, stream>>>(K, invF, R,
                                                                    out);
  } else {
    float* invF = (float*)d_ws;
    float* R = invF + (size_t)BATCH * N;
    float* part = R + (size_t)BATCH * N;
    constexpr int RPW = 8;
    constexpr int CH = N / RPW;
    init_R_kernel<<<dim3(16), dim3(256), 0, stream>>>(R);
    for (int it = 0; it < NITERS; ++it) {
      row_fb_kernel<RPW>
          <<<dim3(N / (4 * RPW), BATCH), dim3(256), 0, stream>>>(z0, R, invF,
                                                                 part);
      combine_fb_kernel<CH>
          <<<dim3((BATCH * N * 4) / 256), dim3(256), 0, stream>>>(part, R);
    }
    final_fb_kernel<<<dim3(N, BATCH), dim3(256), 0, stream>>>(z0, invF, R,
                                                              out);
  }
}

// Round 4
// 521.766 us; speedup vs baseline: 1.8742x; 1.0403x over previous
//
#include <hip/hip_runtime.h>
#include <hip/hip_fp16.h>

#define BATCH 8
#define N 2048
#define NITERS 20

// ---------------------------------------------------------------------------
// Linear-domain Sinkhorn (matrix scaling), fp16 kernel matrix:
//   K = exp(z0) (fp16), KT = K^T (fp16)   [one-time fused precompute]
//   repeat 20x:  invF_i = 1 / sum_j K_ij  * R_j      (row GEMV)
//                R_j    = 1 / sum_i KT_ji * invF_i   (col GEMV, row-major KT)
//   out_ij = K_ij * invF_i * R_j
// K in [4e-3, 3e2] -> fp16-safe (verified: absmax 1.2e-4 vs 1.04e-3 thresh).
// K + KT = 134 MB -> Infinity-Cache resident across all 40 GEMV phases.
// ---------------------------------------------------------------------------

struct alignas(16) Half8 {
  __half h[8];
};

static __device__ __forceinline__ float wave_sum(float v) {
#pragma unroll
  for (int o = 32; o > 0; o >>= 1) v += __shfl_xor(v, o, 64);
  return v;
}

// Fused: K = exp(z0) fp16, KT = K^T fp16, R = 1. 64x64 fp32 LDS tile,
// stride 65 (phase-2 bank = (8q+c+r)%32 -> worst 2-way = free).
__global__ __launch_bounds__(256) void exp_transpose_kernel(
    const float* __restrict__ z0, __half* __restrict__ K,
    __half* __restrict__ KT, float* __restrict__ R) {
  __shared__ float t[64][65];
  const int b = blockIdx.z;
  const int R0 = blockIdx.y * 64, C0 = blockIdx.x * 64;
  const int q = threadIdx.x & 7;   // col-group of 8
  const int r = threadIdx.x >> 3;  // 0..31

  // prefetch both rows (4 x float4 in flight)
  float4 za[2], zb[2];
#pragma unroll
  for (int p = 0; p < 2; ++p) {
    const float* src =
        z0 + ((size_t)b * N + R0 + r + 32 * p) * N + C0 + q * 8;
    za[p] = *reinterpret_cast<const float4*>(src);
    zb[p] = *reinterpret_cast<const float4*>(src + 4);
  }
#pragma unroll
  for (int p = 0; p < 2; ++p) {
    const int row = r + 32 * p;
    float e[8];
    e[0] = __expf(za[p].x);
    e[1] = __expf(za[p].y);
    e[2] = __expf(za[p].z);
    e[3] = __expf(za[p].w);
    e[4] = __expf(zb[p].x);
    e[5] = __expf(zb[p].y);
    e[6] = __expf(zb[p].z);
    e[7] = __expf(zb[p].w);
    Half8 hk;
#pragma unroll
    for (int c = 0; c < 8; ++c) hk.h[c] = __float2half_rn(e[c]);
    *reinterpret_cast<Half8*>(K + ((size_t)b * N + R0 + row) * N + C0 +
                              q * 8) = hk;
#pragma unroll
    for (int c = 0; c < 8; ++c) t[row][q * 8 + c] = e[c];
  }
  __syncthreads();
#pragma unroll
  for (int p = 0; p < 2; ++p) {
    const int jr = r + 32 * p;  // KT row within tile == original column
    Half8 hk;
#pragma unroll
    for (int c = 0; c < 8; ++c) hk.h[c] = __float2half_rn(t[q * 8 + c][jr]);
    *reinterpret_cast<Half8*>(KT + ((size_t)b * N + C0 + jr) * N + R0 +
                              q * 8) = hk;
  }
  // fold in R = 1 init (covers all N per batch across blockIdx.y)
  if (blockIdx.x == 0 && threadIdx.x < 16) {
    reinterpret_cast<float4*>(R + (size_t)b * N + R0)[threadIdx.x] =
        make_float4(1.f, 1.f, 1.f, 1.f);
  }
}

// o[b][row] = 1 / sum_j M[b][row][j] * v[b][j]. Two rows per wave, no LDS:
// v is 8 KB/batch and L1-resident; 8 K-loads in flight per wave.
__global__ __launch_bounds__(256) void gemv_recip_kernel(
    const __half* __restrict__ M, const float* __restrict__ v,
    float* __restrict__ o) {
  const int lane = threadIdx.x & 63;
  const int w = threadIdx.x >> 6;
  const int b = blockIdx.y;
  const int row0 = (blockIdx.x * 4 + w) * 2;

  const float4* m0 =
      reinterpret_cast<const float4*>(M + ((size_t)b * N + row0) * N);
  const float4* m1 =
      reinterpret_cast<const float4*>(M + ((size_t)b * N + row0 + 1) * N);
  float4 ra[4], rb[4];
#pragma unroll
  for (int c = 0; c < 4; ++c) ra[c] = m0[c * 64 + lane];
#pragma unroll
  for (int c = 0; c < 4; ++c) rb[c] = m1[c * 64 + lane];

  const float4* v4 = reinterpret_cast<const float4*>(v + (size_t)b * N);
  float s0a = 0.f, s0b = 0.f, s1a = 0.f, s1b = 0.f;
#pragma unroll
  for (int c = 0; c < 4; ++c) {
    const float4 va = v4[c * 128 + lane * 2];
    const float4 vb = v4[c * 128 + lane * 2 + 1];
    const __half2* ha = reinterpret_cast<const __half2*>(&ra[c]);
    const __half2* hb = reinterpret_cast<const __half2*>(&rb[c]);
    float2 f;
    f = __half22float2(ha[0]); s0a += f.x * va.x; s0b += f.y * va.y;
    f = __half22float2(ha[1]); s0a += f.x * va.z; s0b += f.y * va.w;
    f = __half22float2(ha[2]); s0a += f.x * vb.x; s0b += f.y * vb.y;
    f = __half22float2(ha[3]); s0a += f.x * vb.z; s0b += f.y * vb.w;
    f = __half22float2(hb[0]); s1a += f.x * va.x; s1b += f.y * va.y;
    f = __half22float2(hb[1]); s1a += f.x * va.z; s1b += f.y * va.w;
    f = __half22float2(hb[2]); s1a += f.x * vb.x; s1b += f.y * vb.y;
    f = __half22float2(hb[3]); s1a += f.x * vb.z; s1b += f.y * vb.w;
  }
  float s0 = s0a + s0b, s1 = s1a + s1b;
#pragma unroll
  for (int off = 32; off > 0; off >>= 1) {
    s0 += __shfl_xor(s0, off, 64);
    s1 += __shfl_xor(s1, off, 64);
  }
  if (lane == 0) {
    *reinterpret_cast<float2*>(o + (size_t)b * N + row0) =
        make_float2(1.0f / s0, 1.0f / s1);
  }
}

// out[b][i][j] = K[b][i][j] * invF[b][i] * R[b][j] (no LDS; R is L1-hot)
__global__ __launch_bounds__(256) void final_fp16_kernel(
    const __half* __restrict__ K, const float* __restrict__ invF,
    const float* __restrict__ R, float* __restrict__ out) {
  const int lane = threadIdx.x & 63;
  const int w = threadIdx.x >> 6;
  const int b = blockIdx.y;
  const int row = blockIdx.x * 4 + w;
  const float fi = invF[(size_t)b * N + row];
  const float4* m4 =
      reinterpret_cast<const float4*>(K + ((size_t)b * N + row) * N);
  const float4* r4 = reinterpret_cast<const float4*>(R + (size_t)b * N);
  float4* o4 = reinterpret_cast<float4*>(out + ((size_t)b * N + row) * N);
#pragma unroll
  for (int c = 0; c < 4; ++c) {
    const float4 raw = m4[c * 64 + lane];
    const float4 va = r4[c * 128 + lane * 2];
    const float4 vb = r4[c * 128 + lane * 2 + 1];
    const __half2* h = reinterpret_cast<const __half2*>(&raw);
    float4 oa, ob;
    float2 f;
    f = __half22float2(h[0]); oa.x = f.x * fi * va.x; oa.y = f.y * fi * va.y;
    f = __half22float2(h[1]); oa.z = f.x * fi * va.z; oa.w = f.y * fi * va.w;
    f = __half22float2(h[2]); ob.x = f.x * fi * vb.x; ob.y = f.y * fi * vb.y;
    f = __half22float2(h[3]); ob.z = f.x * fi * vb.z; ob.w = f.y * fi * vb.w;
    o4[(c * 64 + lane) * 2 + 0] = oa;
    o4[(c * 64 + lane) * 2 + 1] = ob;
  }
}

// ------------------------- fallback (small ws) ------------------------------
static __device__ __forceinline__ float wave_sum_fb(float v) {
#pragma unroll
  for (int o = 32; o > 0; o >>= 1) v += __shfl_xor(v, o, 64);
  return v;
}

__global__ __launch_bounds__(256) void init_R_kernel(float* __restrict__ R) {
  const int i = blockIdx.x * 256 + threadIdx.x;
  if (i < (BATCH * N) / 4)
    reinterpret_cast<float4*>(R)[i] = make_float4(1.f, 1.f, 1.f, 1.f);
}

template <int RPW>
__global__ __launch_bounds__(256) void row_fb_kernel(
    const float* __restrict__ z0, const float* __restrict__ R,
    float* __restrict__ invF, float* __restrict__ part) {
  constexpr int CH = N / RPW;
  const int lane = threadIdx.x & 63;
  const int w = threadIdx.x >> 6;
  const int b = blockIdx.y;
  const int chunk = blockIdx.x * 4 + w;
  const int row0 = chunk * RPW;
  const float4* r4 = reinterpret_cast<const float4*>(R + (size_t)b * N);
  float4 rv[8], acc[8];
#pragma unroll
  for (int k = 0; k < 8; ++k) {
    rv[k] = r4[lane + 64 * k];
    acc[k] = make_float4(0.f, 0.f, 0.f, 0.f);
  }
  for (int r = 0; r < RPW; ++r) {
    const int row = row0 + r;
    const float4* z4 =
        reinterpret_cast<const float4*>(z0 + ((size_t)b * N + row) * N);
    float4 zv[8];
#pragma unroll
    for (int k = 0; k < 8; ++k) {
      zv[k] = z4[lane + 64 * k];
      zv[k].x = __expf(zv[k].x); zv[k].y = __expf(zv[k].y);
      zv[k].z = __expf(zv[k].z); zv[k].w = __expf(zv[k].w);
    }
    float s0 = 0.f, s1 = 0.f;
#pragma unroll
    for (int k = 0; k < 8; ++k) {
      s0 += zv[k].x * rv[k].x; s1 += zv[k].y * rv[k].y;
      s0 += zv[k].z * rv[k].z; s1 += zv[k].w * rv[k].w;
    }
    const float inv = 1.0f / wave_sum_fb(s0 + s1);
    if (lane == 0) invF[(size_t)b * N + row] = inv;
#pragma unroll
    for (int k = 0; k < 8; ++k) {
      acc[k].x += zv[k].x * inv; acc[k].y += zv[k].y * inv;
      acc[k].z += zv[k].z * inv; acc[k].w += zv[k].w * inv;
    }
  }
  float4* p4 = reinterpret_cast<float4*>(part + ((size_t)b * CH + chunk) * N);
#pragma unroll
  for (int k = 0; k < 8; ++k) p4[lane + 64 * k] = acc[k];
}

template <int CH>
__global__ __launch_bounds__(256) void combine_fb_kernel(
    const float* __restrict__ part, float* __restrict__ R) {
  const int gid = blockIdx.x * 256 + threadIdx.x;
  const int col_id = gid >> 2;
  const int sub = gid & 3;
  const int b = col_id >> 11;
  const int j = col_id & (N - 1);
  const float* p = part + (size_t)b * CH * N + j + (size_t)sub * N;
  float s = 0.f;
#pragma unroll
  for (int c = 0; c < CH / 4; ++c) s += p[(size_t)c * 4 * N];
  s += __shfl_xor(s, 1, 64);
  s += __shfl_xor(s, 2, 64);
  if (sub == 0) R[col_id] = 1.0f / s;
}

__global__ __launch_bounds__(256) void final_fb_kernel(
    const float* __restrict__ z0, const float* __restrict__ invF,
    const float* __restrict__ R, float* __restrict__ out) {
  const int b = blockIdx.y;
  const int row = blockIdx.x;
  const float fi = invF[(size_t)b * N + row];
  const float4* z4 =
      reinterpret_cast<const float4*>(z0 + ((size_t)b * N + row) * N);
  const float4* r4 = reinterpret_cast<const float4*>(R + (size_t)b * N);
  float4* o4 = reinterpret_cast<float4*>(out + ((size_t)b * N + row) * N);
#pragma unroll
  for (int k = 0; k < 2; ++k) {
    const int i = threadIdx.x + 256 * k;
    const float4 z = z4[i];
    const float4 r = r4[i];
    float4 o;
    o.x = __expf(z.x) * fi * r.x; o.y = __expf(z.y) * fi * r.y;
    o.z = __expf(z.z) * fi * r.z; o.w = __expf(z.w) * fi * r.w;
    o4[i] = o;
  }
}

extern "C" void kernel_launch(void* const* d_in, const int* in_sizes, int n_in,
                              void* d_out, int out_size, void* d_ws,
                              size_t ws_size, hipStream_t stream) {
  const float* z0 = (const float*)d_in[0];
  float* out = (float*)d_out;

  const size_t KE = (size_t)BATCH * N * N;  // elements per matrix
  const size_t need =
      2 * KE * sizeof(__half) + 2 * (size_t)BATCH * N * sizeof(float);

  if (ws_size >= need) {
    __half* K = (__half*)d_ws;
    __half* KT = K + KE;
    float* invF = (float*)(KT + KE);
    float* R = invF + (size_t)BATCH * N;

    exp_transpose_kernel<<<dim3(32, 32, 8), dim3(256), 0, stream>>>(z0, K, KT,
                                                                    R);
    for (int it = 0; it < NITERS; ++it) {
      gemv_recip_kernel<<<dim3(N / 8, BATCH), dim3(256), 0, stream>>>(K, R,
                                                                      invF);
      gemv_recip_kernel<<<dim3(N / 8, BATCH), dim3(256), 0, stream>>>(KT, invF,
                                                                      R);
    }
    final_fp16_kernel<<<dim3(N / 4, BATCH), dim3(256), 0, stream>>>(K, invF, R,
                                                                    out);
  } else {
    float* invF = (float*)d_ws;
    float* R = invF + (size_t)BATCH * N;
    float* part = R + (size_t)BATCH * N;
    constexpr int RPW = 8;
    constexpr int CH = N / RPW;
    init_R_kernel<<<dim3(16), dim3(256), 0, stream>>>(R);
    for (int it = 0; it < NITERS; ++it) {
      row_fb_kernel<RPW>
          <<<dim3(N / (4 * RPW), BATCH), dim3(256), 0, stream>>>(z0, R, invF,
                                                                 part);
      combine_fb_kernel<CH>
          <<<dim3((BATCH * N * 4) / 256), dim3(256), 0, stream>>>(part, R);
    }
    final_fb_kernel<<<dim3(N, BATCH), dim3(256), 0, stream>>>(z0, invF, R,
                                                              out);
  }
}